// Round 8
// baseline (3294.810 us; speedup 1.0000x reference)
//
#include <hip/hip_runtime.h>
#include <math.h>

typedef unsigned long long u64;

#define S_LEN 1024
#define E_DIM 512
#define H_DIM 512
#define G3    1536   // 3*H
#define D_DIM 1024

#define NCHAIN 4
#define WPC    32    // workgroups per GRU chain (128 blocks total, co-resident on 256 CUs)

// ---------------------------------------------------------------------------
// Phase 1: gi[p][t][j] = bih_p[j] + sum_k emb[sent[t],k] * Wih_p[j,k]
// Tiled fp32 GEMM, TM=TN=64, BK=32, 256 threads, 4x4 micro-tile per thread.
// (verbatim round-0 kernel — verified, ~250 us)
// ---------------------------------------------------------------------------
#define TM 64
#define TN 64
#define BK 32

__global__ __launch_bounds__(256) void gi_gemm_kernel(
    const int* __restrict__ sent, const float* __restrict__ emb,
    const float* __restrict__ Wih0, const float* __restrict__ bih0,
    const float* __restrict__ Wih1, const float* __restrict__ bih1,
    const float* __restrict__ Wih2, const float* __restrict__ bih2,
    const float* __restrict__ Wih3, const float* __restrict__ bih3,
    float* __restrict__ gi)
{
    __shared__ float As[BK][TM + 1];
    __shared__ float Bs[BK][TN + 1];
    __shared__ int   rows[TM];

    const int blocks_t = S_LEN / TM;   // 16
    const int blocks_j = G3 / TN;      // 24
    int b   = blockIdx.x;
    int p   = b / (blocks_t * blocks_j);
    int rem = b % (blocks_t * blocks_j);
    int bt  = rem / blocks_j;
    int bj  = rem % blocks_j;

    const float* Wih = (p == 0) ? Wih0 : (p == 1) ? Wih1 : (p == 2) ? Wih2 : Wih3;
    const float* bih = (p == 0) ? bih0 : (p == 1) ? bih1 : (p == 2) ? bih2 : bih3;

    int tid = threadIdx.x;
    if (tid < TM) rows[tid] = sent[bt * TM + tid];
    __syncthreads();

    int tt = (tid >> 4) * 4;   // local t offset of micro-tile
    int jj = (tid & 15) * 4;   // local j offset of micro-tile
    float acc[4][4] = {{0.f}};

    int lr = tid >> 2;         // 0..63 (row within tile)
    int lc = (tid & 3) * 8;    // 0,8,16,24 (col chunk)

    for (int k0 = 0; k0 < E_DIM; k0 += BK) {
        const float* asrc = emb + (size_t)rows[lr] * E_DIM + (k0 + lc);
        float4 a0 = *(const float4*)asrc;
        float4 a1 = *(const float4*)(asrc + 4);
        const float* bsrc = Wih + (size_t)(bj * TN + lr) * E_DIM + (k0 + lc);
        float4 b0 = *(const float4*)bsrc;
        float4 b1 = *(const float4*)(bsrc + 4);

        As[lc+0][lr]=a0.x; As[lc+1][lr]=a0.y; As[lc+2][lr]=a0.z; As[lc+3][lr]=a0.w;
        As[lc+4][lr]=a1.x; As[lc+5][lr]=a1.y; As[lc+6][lr]=a1.z; As[lc+7][lr]=a1.w;
        Bs[lc+0][lr]=b0.x; Bs[lc+1][lr]=b0.y; Bs[lc+2][lr]=b0.z; Bs[lc+3][lr]=b0.w;
        Bs[lc+4][lr]=b1.x; Bs[lc+5][lr]=b1.y; Bs[lc+6][lr]=b1.z; Bs[lc+7][lr]=b1.w;
        __syncthreads();

        #pragma unroll
        for (int kk = 0; kk < BK; ++kk) {
            float av[4], bv[4];
            #pragma unroll
            for (int e = 0; e < 4; ++e) { av[e] = As[kk][tt+e]; bv[e] = Bs[kk][jj+e]; }
            #pragma unroll
            for (int i = 0; i < 4; ++i)
                #pragma unroll
                for (int j2 = 0; j2 < 4; ++j2)
                    acc[i][j2] = fmaf(av[i], bv[j2], acc[i][j2]);
        }
        __syncthreads();
    }

    float* gout = gi + (size_t)p * S_LEN * G3;
    int jbase = bj * TN + jj;
    float bb0 = bih[jbase+0], bb1 = bih[jbase+1], bb2 = bih[jbase+2], bb3 = bih[jbase+3];
    #pragma unroll
    for (int i = 0; i < 4; ++i) {
        int t = bt * TM + tt + i;
        float4 v = make_float4(acc[i][0]+bb0, acc[i][1]+bb1, acc[i][2]+bb2, acc[i][3]+bb3);
        *(float4*)(gout + (size_t)t * G3 + jbase) = v;
    }
}

// ---------------------------------------------------------------------------
// Fast gate math (verified rounds 5-7: passed, absmax 0.0).
// ---------------------------------------------------------------------------
__device__ __forceinline__ float fast_sigmoid(float x) {
    return __builtin_amdgcn_rcpf(1.f + __expf(-x));
}
__device__ __forceinline__ float fast_tanh(float x) {
    return 1.f - 2.f * __builtin_amdgcn_rcpf(1.f + __expf(2.f * x));
}
__device__ __forceinline__ float dot4(float4 a, float4 b, float acc) {
    acc = fmaf(a.x, b.x, acc);
    acc = fmaf(a.y, b.y, acc);
    acc = fmaf(a.z, b.z, acc);
    acc = fmaf(a.w, b.w, acc);
    return acc;
}

// ---------------------------------------------------------------------------
// Phase 2: 4 independent GRU recurrences, persistent kernel, BARRIER-FREE.
//
// Exchange protocol unchanged from the verified rounds 0/4/5: hpk[c][par][i]
// is a 64-bit slot {tag:u32 = step, val:f32}; relaxed agent-scope atomic
// store to publish; tag rides with the value -> fence-free; parity
// double-buffer + exact-tag match; 0xAA poison never matches; monotone tags
// -> graph-replay safe. DENSE layout (round-7 striding reverted: it pushed
// poll traffic out of the LLC, FETCH 103MB -> 1.09GB).
//
// NEW: readers poll their needed slots DIRECTLY. Each thread consumes the
// same 32 h-elements it previously read from LDS (cols 4r+64k+e, e=0..3,
// k=0..7); it now loads those 32 slots with relaxed agent-scope atomic
// loads, batched (32 independent loads -> one latency round) and re-issued
// until all 32 tags == s. Value+tag arrive in the same 8B load, so data is
// usable the instant it is detected:
//   - no __syncthreads in the loop (round-5 barrier made all 4 waves wait
//     for the globally slowest of 512 slots)
//   - no global->LDS->register double hop
//   - waves decouple; each waits only on its own 32 producers
// The publisher's own h short-circuits through a register (hv_reg), not LDS.
// Coalescing: per load instruction the 16 r-lanes hit 16 consecutive 8B
// addresses (128B segment, q-duplicates broadcast).
// Arithmetic (k-order, xyzw, shfl_down 8/4/2/1 tree, gates) is bitwise
// identical to round 5 -> absmax 0.0 expected.
// ---------------------------------------------------------------------------
__global__ __launch_bounds__(256, 1) void gru_scan_kernel(
    const float* __restrict__ Whh0, const float* __restrict__ bhh0,
    const float* __restrict__ Whh1, const float* __restrict__ bhh1,
    const float* __restrict__ Whh2, const float* __restrict__ bhh2,
    const float* __restrict__ Whh3, const float* __restrict__ bhh3,
    const float* __restrict__ gi,
    u64* __restrict__ hpk)             // [4][2][512] dense {tag,val} slots
{
    int b = blockIdx.x;
    int c = b / WPC;
    int w = b % WPC;
    const float* Whh = (c==0)?Whh0:(c==1)?Whh1:(c==2)?Whh2:Whh3;
    const float* bhh = (c==0)?bhh0:(c==1)?bhh1:(c==2)?bhh2:bhh3;
    const float* gic = gi + (size_t)c * S_LEN * G3;
    u64* hp = hpk + (size_t)c * 2 * H_DIM;
    const bool fwd = ((c & 1) == 0);   // chains 0 (ctx_f) and 2 (qry_f) are forward

    int tid  = threadIdx.x;
    int wv   = tid >> 6;
    int lane = tid & 63;
    int q    = lane >> 4;      // lane-group = which of the wave's 4 outputs
    int r    = lane & 15;      // position within group
    int base_i = w * 16 + wv * 4;
    int my_i   = base_i + q;   // output index this group computes
    bool pub   = (r == 0);     // lanes 0,16,32,48 publish

    // Weights: group q needs row (g*512 + my_i); lane r covers columns
    // {4r + 64k + e : k=0..7, e=0..3} as 8 float4s. 96 floats/thread.
    float4 wregv[3][8];
    #pragma unroll
    for (int g = 0; g < 3; ++g) {
        const float* rowp = Whh + (size_t)(g * H_DIM + my_i) * H_DIM;
        #pragma unroll
        for (int k = 0; k < 8; ++k)
            wregv[g][k] = *(const float4*)(rowp + 4 * r + 64 * k);
    }

    float bh_r=0.f, bh_z=0.f, bh_n=0.f;
    float gr=0.f, gz=0.f, gn=0.f;
    if (pub) {
        bh_r = bhh[my_i]; bh_z = bhh[H_DIM + my_i]; bh_n = bhh[2*H_DIM + my_i];
        int t0 = fwd ? 0 : (S_LEN - 1);
        const float* g0 = gic + (size_t)t0 * G3;
        gr = g0[my_i]; gz = g0[H_DIM + my_i]; gn = g0[2*H_DIM + my_i];
    }

    float hv_reg = 0.f;   // publisher's own h (h_0 = 0); replaces the LDS hop

    for (int s = 0; s < S_LEN; ++s) {
        int pb = s & 1;

        // Early gi prefetch for step s+1: issued first so its HBM latency
        // flies under the poll round below. Rotated in at publish time.
        float ngr = 0.f, ngz = 0.f, ngn = 0.f;
        if (pub && s + 1 < S_LEN) {
            int tn = fwd ? (s + 1) : (S_LEN - 2 - s);
            const float* gnx = gic + (size_t)tn * G3;
            ngr = gnx[my_i]; ngz = gnx[H_DIM + my_i]; ngn = gnx[2*H_DIM + my_i];
        }

        float acc0 = 0.f, acc1 = 0.f, acc2 = 0.f;
        if (s > 0) {
            // Direct poll of this thread's 32 input slots. Batch-load all 32
            // (independent relaxed atomics -> one pipelined latency round),
            // then check tags; repeat until every tag matches s.
            const u64* srcp = hp + (size_t)pb * H_DIM + 4 * r;
            u64 sv[32];
            for (;;) {
                #pragma unroll
                for (int k = 0; k < 8; ++k)
                    #pragma unroll
                    for (int e = 0; e < 4; ++e)
                        sv[k * 4 + e] = __hip_atomic_load(srcp + 64 * k + e,
                                                          __ATOMIC_RELAXED, __HIP_MEMORY_SCOPE_AGENT);
                unsigned ok = 1u;
                #pragma unroll
                for (int i = 0; i < 32; ++i)
                    ok &= ((unsigned)(sv[i] >> 32) == (unsigned)s) ? 1u : 0u;
                if (ok) break;
            }
            // Matvec: identical order to round 5 (k-major, xyzw).
            #pragma unroll
            for (int k = 0; k < 8; ++k) {
                float4 hfv = make_float4(
                    __uint_as_float((unsigned)sv[k*4+0]),
                    __uint_as_float((unsigned)sv[k*4+1]),
                    __uint_as_float((unsigned)sv[k*4+2]),
                    __uint_as_float((unsigned)sv[k*4+3]));
                acc0 = dot4(wregv[0][k], hfv, acc0);
                acc1 = dot4(wregv[1][k], hfv, acc1);
                acc2 = dot4(wregv[2][k], hfv, acc2);
            }
        }
        // Reduce within the 16-lane group via down-shifts into lane r=0
        // (the publisher) — verified round 5. (s=0: all-zero partials.)
        #pragma unroll
        for (int off = 8; off >= 1; off >>= 1) {
            acc0 += __shfl_down(acc0, off, 16);
            acc1 += __shfl_down(acc1, off, 16);
            acc2 += __shfl_down(acc2, off, 16);
        }

        if (pub) {
            float rr = fast_sigmoid(gr + acc0 + bh_r);
            float zz = fast_sigmoid(gz + acc1 + bh_z);
            float nn = fast_tanh(gn + rr * (acc2 + bh_n));
            float hn = (1.f - zz) * nn + zz * hv_reg;
            hv_reg = hn;   // own value stays in-register for the next step
            // Publish device-wide with the step tag riding along.
            union { float f; unsigned u; } cv; cv.f = hn;
            u64 pk = ((u64)(unsigned)(s + 1) << 32) | (u64)cv.u;
            __hip_atomic_store(hp + (size_t)(pb ^ 1) * H_DIM + my_i, pk,
                               __ATOMIC_RELAXED, __HIP_MEMORY_SCOPE_AGENT);
            // Rotate in the prefetched gi values for the next step.
            gr = ngr; gz = ngz; gn = ngn;
        }
    }
}

// ---------------------------------------------------------------------------
// Phase 3a: h1 = relu(d1_w @ rep + d1_b); rep[j] = val(hpk[j>>9][0][j&511])
// (final h_1024 sits in parity-0 slots, tag 1024). One wave per output row.
// ---------------------------------------------------------------------------
__global__ __launch_bounds__(256) void dense1_kernel(
    const float* __restrict__ d1w, const float* __restrict__ d1b,
    const u64* __restrict__ hpk, float* __restrict__ h1)
{
    int wv = threadIdx.x >> 6, lane = threadIdx.x & 63;
    int row = blockIdx.x * 4 + wv;
    const float* wr = d1w + (size_t)row * (4 * H_DIM);
    float sum = 0.f;
    #pragma unroll
    for (int q = 0; q < 32; ++q) {
        int j = lane + q * 64;
        int cc = j >> 9;
        float h = __uint_as_float((unsigned)hpk[(size_t)cc * 2 * H_DIM + (j & 511)]);
        sum = fmaf(wr[j], h, sum);
    }
    #pragma unroll
    for (int off = 32; off >= 1; off >>= 1) sum += __shfl_xor(sum, off, 64);
    if (lane == 0) h1[row] = fmaxf(sum + d1b[row], 0.f);
}

// Phase 3b: out = sigmoid(d2_w @ h1 + d2_b), one block.
__global__ __launch_bounds__(256) void dense2_kernel(
    const float* __restrict__ d2w, const float* __restrict__ d2b,
    const float* __restrict__ h1, float* __restrict__ out)
{
    __shared__ float red[4];
    int tid = threadIdx.x, lane = tid & 63, wv = tid >> 6;
    float sum = 0.f;
    #pragma unroll
    for (int q = 0; q < 4; ++q) { int j = tid + q * 256; sum = fmaf(d2w[j], h1[j], sum); }
    #pragma unroll
    for (int off = 32; off >= 1; off >>= 1) sum += __shfl_xor(sum, off, 64);
    if (lane == 0) red[wv] = sum;
    __syncthreads();
    if (tid == 0) {
        float t = red[0] + red[1] + red[2] + red[3] + d2b[0];
        out[0] = 1.f / (1.f + expf(-t));
    }
}

// ---------------------------------------------------------------------------
extern "C" void kernel_launch(void* const* d_in, const int* in_sizes, int n_in,
                              void* d_out, int out_size, void* d_ws, size_t ws_size,
                              hipStream_t stream) {
    const int*   sent = (const int*)d_in[0];
    const float* emb  = (const float*)d_in[1];
    const float* Wih[4], *Whh[4], *bih[4], *bhh[4];
    for (int p = 0; p < 4; ++p) {
        Wih[p] = (const float*)d_in[2 + 4*p + 0];
        Whh[p] = (const float*)d_in[2 + 4*p + 1];
        bih[p] = (const float*)d_in[2 + 4*p + 2];
        bhh[p] = (const float*)d_in[2 + 4*p + 3];
    }
    const float* d1w = (const float*)d_in[18];
    const float* d1b = (const float*)d_in[19];
    const float* d2w = (const float*)d_in[20];
    const float* d2b = (const float*)d_in[21];
    float* out = (float*)d_out;

    // Workspace layout (round-0/5 verified):
    //   gi    : 4*1024*1536 floats = 25165824 B
    //   hpk   : 4*2*512 u64        = 32768 B   (dense, self-tagged; no init
    //                                           needed, 0xAA poison never
    //                                           matches a tag)
    //   h1    : 1024 floats        = 4096 B
    float* gi  = (float*)d_ws;
    u64*   hpk = (u64*)((char*)d_ws + (size_t)NCHAIN * S_LEN * G3 * sizeof(float));
    float* h1  = (float*)((char*)hpk + (size_t)NCHAIN * 2 * H_DIM * sizeof(u64));

    gi_gemm_kernel<<<NCHAIN * (S_LEN/TM) * (G3/TN), 256, 0, stream>>>(
        sent, emb,
        Wih[0], bih[0], Wih[1], bih[1], Wih[2], bih[2], Wih[3], bih[3], gi);

    gru_scan_kernel<<<NCHAIN * WPC, 256, 0, stream>>>(
        Whh[0], bhh[0], Whh[1], bhh[1], Whh[2], bhh[2], Whh[3], bhh[3],
        gi, hpk);

    dense1_kernel<<<D_DIM / 4, 256, 0, stream>>>(d1w, d1b, hpk, h1);
    dense2_kernel<<<1, 256, 0, stream>>>(d2w, d2b, h1, out);
}

// Round 9
// 2020.286 us; speedup vs baseline: 1.6309x; 1.6309x over previous
//
#include <hip/hip_runtime.h>
#include <math.h>

typedef unsigned long long u64;

#define S_LEN 1024
#define E_DIM 512
#define H_DIM 512
#define G3    1536   // 3*H
#define D_DIM 1024

#define NCHAIN 4
#define WPC    32    // workgroups per GRU chain (128 blocks total, co-resident on 256 CUs)

// ---------------------------------------------------------------------------
// Phase 1: gi[p][t][j] = bih_p[j] + sum_k emb[sent[t],k] * Wih_p[j,k]
// Tiled fp32 GEMM, TM=TN=64, BK=32, 256 threads, 4x4 micro-tile per thread.
// (verbatim round-0 kernel — verified)
// ---------------------------------------------------------------------------
#define TM 64
#define TN 64
#define BK 32

__global__ __launch_bounds__(256) void gi_gemm_kernel(
    const int* __restrict__ sent, const float* __restrict__ emb,
    const float* __restrict__ Wih0, const float* __restrict__ bih0,
    const float* __restrict__ Wih1, const float* __restrict__ bih1,
    const float* __restrict__ Wih2, const float* __restrict__ bih2,
    const float* __restrict__ Wih3, const float* __restrict__ bih3,
    float* __restrict__ gi)
{
    __shared__ float As[BK][TM + 1];
    __shared__ float Bs[BK][TN + 1];
    __shared__ int   rows[TM];

    const int blocks_t = S_LEN / TM;   // 16
    const int blocks_j = G3 / TN;      // 24
    int b   = blockIdx.x;
    int p   = b / (blocks_t * blocks_j);
    int rem = b % (blocks_t * blocks_j);
    int bt  = rem / blocks_j;
    int bj  = rem % blocks_j;

    const float* Wih = (p == 0) ? Wih0 : (p == 1) ? Wih1 : (p == 2) ? Wih2 : Wih3;
    const float* bih = (p == 0) ? bih0 : (p == 1) ? bih1 : (p == 2) ? bih2 : bih3;

    int tid = threadIdx.x;
    if (tid < TM) rows[tid] = sent[bt * TM + tid];
    __syncthreads();

    int tt = (tid >> 4) * 4;   // local t offset of micro-tile
    int jj = (tid & 15) * 4;   // local j offset of micro-tile
    float acc[4][4] = {{0.f}};

    int lr = tid >> 2;         // 0..63 (row within tile)
    int lc = (tid & 3) * 8;    // 0,8,16,24 (col chunk)

    for (int k0 = 0; k0 < E_DIM; k0 += BK) {
        const float* asrc = emb + (size_t)rows[lr] * E_DIM + (k0 + lc);
        float4 a0 = *(const float4*)asrc;
        float4 a1 = *(const float4*)(asrc + 4);
        const float* bsrc = Wih + (size_t)(bj * TN + lr) * E_DIM + (k0 + lc);
        float4 b0 = *(const float4*)bsrc;
        float4 b1 = *(const float4*)(bsrc + 4);

        As[lc+0][lr]=a0.x; As[lc+1][lr]=a0.y; As[lc+2][lr]=a0.z; As[lc+3][lr]=a0.w;
        As[lc+4][lr]=a1.x; As[lc+5][lr]=a1.y; As[lc+6][lr]=a1.z; As[lc+7][lr]=a1.w;
        Bs[lc+0][lr]=b0.x; Bs[lc+1][lr]=b0.y; Bs[lc+2][lr]=b0.z; Bs[lc+3][lr]=b0.w;
        Bs[lc+4][lr]=b1.x; Bs[lc+5][lr]=b1.y; Bs[lc+6][lr]=b1.z; Bs[lc+7][lr]=b1.w;
        __syncthreads();

        #pragma unroll
        for (int kk = 0; kk < BK; ++kk) {
            float av[4], bv[4];
            #pragma unroll
            for (int e = 0; e < 4; ++e) { av[e] = As[kk][tt+e]; bv[e] = Bs[kk][jj+e]; }
            #pragma unroll
            for (int i = 0; i < 4; ++i)
                #pragma unroll
                for (int j2 = 0; j2 < 4; ++j2)
                    acc[i][j2] = fmaf(av[i], bv[j2], acc[i][j2]);
        }
        __syncthreads();
    }

    float* gout = gi + (size_t)p * S_LEN * G3;
    int jbase = bj * TN + jj;
    float bb0 = bih[jbase+0], bb1 = bih[jbase+1], bb2 = bih[jbase+2], bb3 = bih[jbase+3];
    #pragma unroll
    for (int i = 0; i < 4; ++i) {
        int t = bt * TM + tt + i;
        float4 v = make_float4(acc[i][0]+bb0, acc[i][1]+bb1, acc[i][2]+bb2, acc[i][3]+bb3);
        *(float4*)(gout + (size_t)t * G3 + jbase) = v;
    }
}

// ---------------------------------------------------------------------------
// Fast gate math (verified rounds 5-8: passed, absmax 0.0).
// ---------------------------------------------------------------------------
__device__ __forceinline__ float fast_sigmoid(float x) {
    return __builtin_amdgcn_rcpf(1.f + __expf(-x));
}
__device__ __forceinline__ float fast_tanh(float x) {
    return 1.f - 2.f * __builtin_amdgcn_rcpf(1.f + __expf(2.f * x));
}

#define HLOAD(p) __hip_atomic_load((p), __ATOMIC_RELAXED, __HIP_MEMORY_SCOPE_AGENT)

// ---------------------------------------------------------------------------
// Phase 2: 4 independent GRU recurrences, persistent kernel, FENCE-FREE sync.
// = round-5 VERIFIED kernel (best measured: scan 1977us) with ONE change:
// the poll is 4-deep software-pipelined.
//
// Exchange protocol unchanged: hpk[c][parity][i] is a 64-bit slot
// {tag:u32 = step, val:f32}; relaxed agent-scope atomic store to publish,
// relaxed agent-scope atomic loads to poll. Tag rides with the value ->
// fence-free. Parity double-buffer + exact-tag match; 0xAA poison never
// matches; monotone tags -> graph-replay safe. DENSE layout (r7 lesson).
// Per-thread 2-slot ferry -> LDS -> barrier (r8 lesson: direct wide polling
// loses; the ferry structure is right).
//
// NEW (pipelined poll): each thread keeps 4 load-pairs to its two slot
// addresses in rotation (8 outstanding loads, fixed names - no arrays).
// Checking the oldest pair waits vmcnt(6), not vmcnt(0), while 3 younger
// pairs remain in flight. Sampling period drops from ~RT (~900cy at the
// memory-side coherence point) to ~RT/4, shrinking both the expected detect
// time and - more importantly - the barrier's max-of-512-slots jitter
// amplification (jitter range ~RT -> ~RT/4). Protocol traffic pattern is
// unchanged except rate (same two dense addresses per thread).
// ---------------------------------------------------------------------------
__global__ __launch_bounds__(256, 1) void gru_scan_kernel(
    const float* __restrict__ Whh0, const float* __restrict__ bhh0,
    const float* __restrict__ Whh1, const float* __restrict__ bhh1,
    const float* __restrict__ Whh2, const float* __restrict__ bhh2,
    const float* __restrict__ Whh3, const float* __restrict__ bhh3,
    const float* __restrict__ gi,
    u64* __restrict__ hpk)             // [4][2][512] dense {tag,val} slots
{
    __shared__ float lds_h[2][H_DIM];

    int b = blockIdx.x;
    int c = b / WPC;
    int w = b % WPC;
    const float* Whh = (c==0)?Whh0:(c==1)?Whh1:(c==2)?Whh2:Whh3;
    const float* bhh = (c==0)?bhh0:(c==1)?bhh1:(c==2)?bhh2:bhh3;
    const float* gic = gi + (size_t)c * S_LEN * G3;
    u64* hp = hpk + (size_t)c * 2 * H_DIM;
    const bool fwd = ((c & 1) == 0);   // chains 0 (ctx_f) and 2 (qry_f) are forward

    int tid  = threadIdx.x;
    int wv   = tid >> 6;
    int lane = tid & 63;
    int q    = lane >> 4;      // lane-group = which of the wave's 4 outputs
    int r    = lane & 15;      // position within group
    int base_i = w * 16 + wv * 4;
    int my_i   = base_i + q;   // output index this group computes
    bool pub   = (r == 0);     // lanes 0,16,32,48 publish

    // Weights: group q needs row (g*512 + my_i); lane r covers columns
    // {4r + 64k + e : k=0..7, e=0..3} as 8 float4s. 96 floats/thread.
    float4 wregv[3][8];
    #pragma unroll
    for (int g = 0; g < 3; ++g) {
        const float* rowp = Whh + (size_t)(g * H_DIM + my_i) * H_DIM;
        #pragma unroll
        for (int k = 0; k < 8; ++k)
            wregv[g][k] = *(const float4*)(rowp + 4 * r + 64 * k);
    }

    float bh_r=0.f, bh_z=0.f, bh_n=0.f;
    float gr=0.f, gz=0.f, gn=0.f;
    if (pub) {
        bh_r = bhh[my_i]; bh_z = bhh[H_DIM + my_i]; bh_n = bhh[2*H_DIM + my_i];
        int t0 = fwd ? 0 : (S_LEN - 1);
        const float* g0 = gic + (size_t)t0 * G3;
        gr = g0[my_i]; gz = g0[H_DIM + my_i]; gn = g0[2*H_DIM + my_i];
    }

    // h_0 = 0 lives in LDS buffer 0.
    lds_h[0][tid]       = 0.f;
    lds_h[0][tid + 256] = 0.f;

    // Each thread ferries slots tid and tid+256.
    int s0 = tid, s1 = tid + 256;
    bool own0 = ((s0 >> 4) == w);
    bool own1 = ((s1 >> 4) == w);

    for (int s = 0; s < S_LEN; ++s) {
        int pb = s & 1;
        if (s > 0) {
            const u64* srcp = hp + (size_t)pb * H_DIM;
            const u64* A = srcp + s0;
            const u64* B = srcp + s1;
            bool p0 = own0, p1 = own1;
            if (!(p0 && p1)) {
                // Prime 4 pairs (8 outstanding loads).
                u64 a0 = HLOAD(A), a1 = HLOAD(B);
                u64 b0 = HLOAD(A), b1 = HLOAD(B);
                u64 c0 = HLOAD(A), c1 = HLOAD(B);
                u64 d0 = HLOAD(A), d1 = HLOAD(B);
                for (;;) {
                    // stage A: check oldest pair (vmcnt(6)), reissue it.
                    if (!p0 && (unsigned)(a0 >> 32) == (unsigned)s) {
                        lds_h[pb][s0] = __uint_as_float((unsigned)a0); p0 = true;
                    }
                    if (!p1 && (unsigned)(a1 >> 32) == (unsigned)s) {
                        lds_h[pb][s1] = __uint_as_float((unsigned)a1); p1 = true;
                    }
                    if (p0 && p1) break;
                    a0 = HLOAD(A); a1 = HLOAD(B);
                    // stage B
                    if (!p0 && (unsigned)(b0 >> 32) == (unsigned)s) {
                        lds_h[pb][s0] = __uint_as_float((unsigned)b0); p0 = true;
                    }
                    if (!p1 && (unsigned)(b1 >> 32) == (unsigned)s) {
                        lds_h[pb][s1] = __uint_as_float((unsigned)b1); p1 = true;
                    }
                    if (p0 && p1) break;
                    b0 = HLOAD(A); b1 = HLOAD(B);
                    // stage C
                    if (!p0 && (unsigned)(c0 >> 32) == (unsigned)s) {
                        lds_h[pb][s0] = __uint_as_float((unsigned)c0); p0 = true;
                    }
                    if (!p1 && (unsigned)(c1 >> 32) == (unsigned)s) {
                        lds_h[pb][s1] = __uint_as_float((unsigned)c1); p1 = true;
                    }
                    if (p0 && p1) break;
                    c0 = HLOAD(A); c1 = HLOAD(B);
                    // stage D
                    if (!p0 && (unsigned)(d0 >> 32) == (unsigned)s) {
                        lds_h[pb][s0] = __uint_as_float((unsigned)d0); p0 = true;
                    }
                    if (!p1 && (unsigned)(d1 >> 32) == (unsigned)s) {
                        lds_h[pb][s1] = __uint_as_float((unsigned)d1); p1 = true;
                    }
                    if (p0 && p1) break;
                    d0 = HLOAD(A); d1 = HLOAD(B);
                }
            }
        }
        __syncthreads();

        // Early gi prefetch: issued before the matvec so its HBM latency
        // overlaps compute AND the next poll wait. NOT drained here — the
        // publish store below does not depend on these loads.
        float ngr = 0.f, ngz = 0.f, ngn = 0.f;
        if (pub && s + 1 < S_LEN) {
            int tn = fwd ? (s + 1) : (S_LEN - 2 - s);
            const float* gnx = gic + (size_t)tn * G3;
            ngr = gnx[my_i]; ngz = gnx[H_DIM + my_i]; ngn = gnx[2*H_DIM + my_i];
        }

        // hv read hoisted: LDS latency overlaps the matvec below.
        float hv = lds_h[pb][my_i];

        // hf: 8 float4 reads, conflict-free (bank-conflict = 0, rounds 3-8).
        float4 hfv[8];
        const float* hbase = &lds_h[pb][0];
        #pragma unroll
        for (int k = 0; k < 8; ++k)
            hfv[k] = *(const float4*)(hbase + 4 * r + 64 * k);

        float acc[3];
        #pragma unroll
        for (int g = 0; g < 3; ++g) {
            float a = 0.f;
            #pragma unroll
            for (int k = 0; k < 8; ++k) {
                a = fmaf(wregv[g][k].x, hfv[k].x, a);
                a = fmaf(wregv[g][k].y, hfv[k].y, a);
                a = fmaf(wregv[g][k].z, hfv[k].z, a);
                a = fmaf(wregv[g][k].w, hfv[k].w, a);
            }
            acc[g] = a;
        }
        // Reduce within the 16-lane group via down-shifts (DPP row_shr:N)
        // into lane r=0 (the publisher) — verified round 5.
        #pragma unroll
        for (int off = 8; off >= 1; off >>= 1)
            #pragma unroll
            for (int g = 0; g < 3; ++g)
                acc[g] += __shfl_down(acc[g], off, 16);

        if (pub) {
            float rr = fast_sigmoid(gr + acc[0] + bh_r);
            float zz = fast_sigmoid(gz + acc[1] + bh_z);
            float nn = fast_tanh(gn + rr * (acc[2] + bh_n));
            float hn = (1.f - zz) * nn + zz * hv;
            // Own value short-circuits through LDS for this block...
            lds_h[pb ^ 1][my_i] = hn;
            // ...and is published device-wide with the step tag riding along.
            union { float f; unsigned u; } cv; cv.f = hn;
            u64 pk = ((u64)(unsigned)(s + 1) << 32) | (u64)cv.u;
            __hip_atomic_store(hp + (size_t)(pb ^ 1) * H_DIM + my_i, pk,
                               __ATOMIC_RELAXED, __HIP_MEMORY_SCOPE_AGENT);
            // Rotate in the prefetched gi values for the next step.
            gr = ngr; gz = ngz; gn = ngn;
        }
    }
}

// ---------------------------------------------------------------------------
// Phase 3a: h1 = relu(d1_w @ rep + d1_b); rep[j] = val(hpk[j>>9][0][j&511])
// (final h_1024 sits in parity-0 slots, tag 1024). One wave per output row.
// ---------------------------------------------------------------------------
__global__ __launch_bounds__(256) void dense1_kernel(
    const float* __restrict__ d1w, const float* __restrict__ d1b,
    const u64* __restrict__ hpk, float* __restrict__ h1)
{
    int wv = threadIdx.x >> 6, lane = threadIdx.x & 63;
    int row = blockIdx.x * 4 + wv;
    const float* wr = d1w + (size_t)row * (4 * H_DIM);
    float sum = 0.f;
    #pragma unroll
    for (int q = 0; q < 32; ++q) {
        int j = lane + q * 64;
        int cc = j >> 9;
        float h = __uint_as_float((unsigned)hpk[(size_t)cc * 2 * H_DIM + (j & 511)]);
        sum = fmaf(wr[j], h, sum);
    }
    #pragma unroll
    for (int off = 32; off >= 1; off >>= 1) sum += __shfl_xor(sum, off, 64);
    if (lane == 0) h1[row] = fmaxf(sum + d1b[row], 0.f);
}

// Phase 3b: out = sigmoid(d2_w @ h1 + d2_b), one block.
__global__ __launch_bounds__(256) void dense2_kernel(
    const float* __restrict__ d2w, const float* __restrict__ d2b,
    const float* __restrict__ h1, float* __restrict__ out)
{
    __shared__ float red[4];
    int tid = threadIdx.x, lane = tid & 63, wv = tid >> 6;
    float sum = 0.f;
    #pragma unroll
    for (int q = 0; q < 4; ++q) { int j = tid + q * 256; sum = fmaf(d2w[j], h1[j], sum); }
    #pragma unroll
    for (int off = 32; off >= 1; off >>= 1) sum += __shfl_xor(sum, off, 64);
    if (lane == 0) red[wv] = sum;
    __syncthreads();
    if (tid == 0) {
        float t = red[0] + red[1] + red[2] + red[3] + d2b[0];
        out[0] = 1.f / (1.f + expf(-t));
    }
}

// ---------------------------------------------------------------------------
extern "C" void kernel_launch(void* const* d_in, const int* in_sizes, int n_in,
                              void* d_out, int out_size, void* d_ws, size_t ws_size,
                              hipStream_t stream) {
    const int*   sent = (const int*)d_in[0];
    const float* emb  = (const float*)d_in[1];
    const float* Wih[4], *Whh[4], *bih[4], *bhh[4];
    for (int p = 0; p < 4; ++p) {
        Wih[p] = (const float*)d_in[2 + 4*p + 0];
        Whh[p] = (const float*)d_in[2 + 4*p + 1];
        bih[p] = (const float*)d_in[2 + 4*p + 2];
        bhh[p] = (const float*)d_in[2 + 4*p + 3];
    }
    const float* d1w = (const float*)d_in[18];
    const float* d1b = (const float*)d_in[19];
    const float* d2w = (const float*)d_in[20];
    const float* d2b = (const float*)d_in[21];
    float* out = (float*)d_out;

    // Workspace layout (round-0/5 verified):
    //   gi    : 4*1024*1536 floats = 25165824 B
    //   hpk   : 4*2*512 u64        = 32768 B   (dense, self-tagged; no init
    //                                           needed, 0xAA poison never
    //                                           matches a tag)
    //   h1    : 1024 floats        = 4096 B
    float* gi  = (float*)d_ws;
    u64*   hpk = (u64*)((char*)d_ws + (size_t)NCHAIN * S_LEN * G3 * sizeof(float));
    float* h1  = (float*)((char*)hpk + (size_t)NCHAIN * 2 * H_DIM * sizeof(u64));

    gi_gemm_kernel<<<NCHAIN * (S_LEN/TM) * (G3/TN), 256, 0, stream>>>(
        sent, emb,
        Wih[0], bih[0], Wih[1], bih[1], Wih[2], bih[2], Wih[3], bih[3], gi);

    gru_scan_kernel<<<NCHAIN * WPC, 256, 0, stream>>>(
        Whh[0], bhh[0], Whh[1], bhh[1], Whh[2], bhh[2], Whh[3], bhh[3],
        gi, hpk);

    dense1_kernel<<<D_DIM / 4, 256, 0, stream>>>(d1w, d1b, hpk, h1);
    dense2_kernel<<<1, 256, 0, stream>>>(d2w, d2b, h1, out);
}